// Round 12
// baseline (283.653 us; speedup 1.0000x reference)
//
#include <hip/hip_runtime.h>

#define B_ 256
#define T_ 2048
#define F_ 20
#define NT (B_*T_)
#define CH 16
#define NCH (T_/CH)   // 128 chunks

typedef __bf16 bf16x8 __attribute__((ext_vector_type(8)));
typedef float  f32x4  __attribute__((ext_vector_type(4)));

__device__ __forceinline__ float ex2(float x){ return __builtin_amdgcn_exp2f(x); }
__device__ __forceinline__ float rcpf_(float x){ return __builtin_amdgcn_rcpf(x); }

// 20*log2(e), 2*log2(e), log2(e)
#define K10F 28.853900817779268f
#define K1F   2.8853900817779268f
#define LOG2E 1.4426950408889634f

__device__ __forceinline__ float hside(float x){ return 1.0f - rcpf_(ex2(K10F*x) + 1.0f); }
__device__ __forceinline__ float tanh_f(float z){ return 1.0f - 2.0f*rcpf_(ex2(K1F*z) + 1.0f); }
__device__ __forceinline__ float sigmoid_f(float z){ return rcpf_(1.0f + ex2(-LOG2E*z)); }

// LDS-only barrier: orders ds ops between stage waves WITHOUT draining vmcnt.
__device__ __forceinline__ void lds_barrier(){
  asm volatile("s_waitcnt lgkmcnt(0)" ::: "memory");
  __builtin_amdgcn_s_barrier();
  asm volatile("" ::: "memory");
}

// ws float layout (t-major r = t*256 + b):
// pT [0,NT) p | wuT [2NT,3NT) | wdT [3NT,4NT) | pk4 [4NT,8NT) float4{A,B,KP,_}
// All produced by fused_kernel, consumed ONLY by final_kernel (kernel-boundary
// visibility). prep_kernel eliminated: scan blocks' idle waves 4..7 stream in->LDS.

// blocks 0..3: pipelined scan; waves 0-3 = R11-verbatim chain stages;
//              waves 4-7 (previously idle) stream in -> ppL ring + pT.
// blocks 4..2051: MFMA MLP, 256 rows/block (R1-verbatim, verified)
__global__ __launch_bounds__(512) void fused_kernel(const float* __restrict__ in,
    const float* __restrict__ w1, const float* __restrict__ b1,
    const float* __restrict__ w2, const float* __restrict__ b2,
    const float* __restrict__ w3, const float* __restrict__ b3,
    float* __restrict__ ws){
  extern __shared__ char sm[];
  float* pk4 = ws + 4*(size_t)NT;

  if (blockIdx.x < 4) {
    // ================== pipelined Xinanjiang scan ==================
    asm volatile("s_setprio 3");            // scan waves win issue arbitration vs MLP waves
    float* pT  = ws;
    float* wuT = ws + 2*(size_t)NT;
    float* wdT = ws + 3*(size_t)NT;
    float*  d1L = (float*)sm;                  // [2][CH][64]   8 KB
    float*  bsQ = (float*)(sm + 8192);         // [4][CH][64]  16 KB
    float2* rhL = (float2*)(sm + 24576);       // [2][CH][64]  16 KB {rp,hrp}
    float2* qbL = (float2*)(sm + 40960);       // [2][CH][64]  16 KB {qv,b2}
    float2* ppL = (float2*)(sm + 57344);       // [2][CH][65]  16.25 KB {pet,p} ring (65-pad)

    int tid = threadIdx.x;
    int wv = tid >> 6, lane = tid & 63;
    int boff = blockIdx.x * 64;
    const float4* in4 = (const float4*)in;

    float wu = 0.0f, wl = 0.0f, wd = 0.0f;

    // ---- prologue: streamer waves (4-7) stage chunk 0 into ppL slot 0 + pT ----
    if (wv >= 4){
      int st = tid - 256;                   // 0..255
      #pragma unroll
      for (int k = 0; k < 4; ++k){
        int u = k*256 + st;                 // 0..1023
        int bl = u >> 4, tl = u & 15;       // batch-in-block, t-in-chunk
        float4 v = in4[((size_t)(boff + bl)*T_ + tl)*5];   // f0..f3: .x=pet,.z=p
        ppL[0*(CH*65) + tl*65 + bl] = make_float2(v.x, v.z);
        pT[tl*B_ + boff + bl] = v.z;
      }
    }
    lds_barrier();

    for (int it = 0; it < NCH + 3; ++it){
      if (wv == 0){
        if (it < NCH){
          int c = it, par = c & 1;
          #pragma unroll
          for (int s = 0; s < CH; ++s){
            float2 pp = ppL[par*(CH*65) + s*65 + lane];   // chunk c from LDS ring
            float pet = pp.x, p = pp.y;
            float d  = wu - pet;
            float r1 = rcpf_(ex2(K10F*d) + 1.0f);
            float d1 = -d*r1;                       // pet - et1
            float base = (p - pet) + d1;            // p - et1
            wu += base;
            wuT[(c*CH + s)*B_ + boff + lane] = wu;
            d1L[par*(CH*64) + s*64 + lane] = d1;
            bsQ[(c&3)*(CH*64) + s*64 + lane] = base;
          }
        }
      } else if (wv == 1){
        if (it >= 1 && it <= NCH){
          int c = it - 1, par = c & 1;
          #pragma unroll
          for (int s = 0; s < CH; ++s){
            float d1 = d1L[par*(CH*64) + s*64 + lane];
            float r2 = rcpf_(ex2(K10F*d1) + 1.0f);
            float rp = fmaf(-d1, r2, d1);             // h(d1)*d1
            float hrp = 1.0f - rcpf_(ex2(K10F*rp) + 1.0f);
            rhL[par*(CH*64) + s*64 + lane] = make_float2(rp, hrp);
          }
        }
      } else if (wv == 2){
        if (it >= 2 && it <= NCH + 1){
          int c = it - 2, par = c & 1;
          #pragma unroll
          for (int s = 0; s < CH; ++s){
            float2 rh  = rhL[par*(CH*64) + s*64 + lane];
            float base = bsQ[(c&3)*(CH*64) + s*64 + lane];
            float d2   = rh.x - wl;
            float r    = rcpf_(ex2(K10F*d2) + 1.0f);
            float et22 = fmaf(d2, r, wl);
            float et2  = rh.y * et22;
            float b2v  = base - et2;
            wl += b2v;
            qbL[par*(CH*64) + s*64 + lane] = make_float2(rh.x - et2, b2v); // qv, b2
          }
        }
      } else if (wv == 3){
        if (it >= 3){
          int c = it - 3, par = c & 1;
          #pragma unroll
          for (int s = 0; s < CH; ++s){
            float2 qb  = qbL[par*(CH*64) + s*64 + lane];
            float hqv  = 1.0f - rcpf_(ex2(K10F*qb.x) + 1.0f);
            float d3   = qb.x - wd;
            float r    = rcpf_(ex2(K10F*d3) + 1.0f);
            float et33 = fmaf(d3, r, wd);
            float et3  = hqv * et33;
            wd += qb.y - et3;
            wdT[(c*CH + s)*B_ + boff + lane] = wd;
          }
        }
      } else {
        // ---- streamer waves 4-7: produce chunk it+1 into ppL slot (it+1)&1 ----
        // Consumer (wv0) is reading slot it&1 this iteration -> no overlap; writes
        // complete before the barrier (lgkmcnt(0)) -> visible at iteration it+1.
        int cs = it + 1;
        if (cs < NCH){
          int st = tid - 256;
          int slot = cs & 1;
          #pragma unroll
          for (int k = 0; k < 4; ++k){
            int u = k*256 + st;
            int bl = u >> 4, tl = u & 15;
            float4 v = in4[((size_t)(boff + bl)*T_ + cs*16 + tl)*5];
            ppL[slot*(CH*65) + tl*65 + bl] = make_float2(v.x, v.z);
            pT[(cs*16 + tl)*B_ + boff + bl] = v.z;
          }
        }
      }
      lds_barrier();   // LDS-only ordering; wuT/wdT/pT stores stay in flight
    }
    return;
  }

  // ================== MFMA MLP path: 32 rows per wave (R1-verbatim) ==================
  // LDS map:
  // w1f [0,8192) | w2f half [8192,24576) | b1s [24576,25600) | b2s [25600,25856)
  // b3s [25856,25888) | hbufA [25888,62752): 8 waves x 32 rows x 72 bf16
  __bf16* w1f   = (__bf16*)sm;
  __bf16* w2f   = (__bf16*)(sm + 8192);
  float*  b1s   = (float*)(sm + 24576);
  float*  b2s   = (float*)(sm + 25600);
  float*  b3s   = (float*)(sm + 25856);
  __bf16* hbufA = (__bf16*)(sm + 25888);

  int tid  = threadIdx.x;
  int lane = tid & 63;
  int wv   = tid >> 6;
  int m    = lane & 15;
  int q    = lane >> 4;
  int r0   = (blockIdx.x - 4)*256 + wv*32;   // t-major r, 32 rows per wave

  // ---- early global loads (latency hidden under staging) ----
  bf16x8 a1[2];
  #pragma unroll
  for (int u = 0; u < 2; ++u){
    int rowA = r0 + u*16 + m;
    int bA = rowA & (B_-1), tA = rowA >> 8;
    const float* ap = in + ((size_t)bA*T_ + tA)*F_ + 5;
    #pragma unroll
    for (int j = 0; j < 8; ++j){
      int k = q*8 + j;
      a1[u][j] = (__bf16)((k < 15) ? ap[k] : 0.0f);
    }
  }
  // w3 B-fragments in registers, split hi+lo bf16 so z3 is f32-accurate.
  bf16x8 w3h[2], w3l[2];
  #pragma unroll
  for (int kb = 0; kb < 2; ++kb){
    #pragma unroll
    for (int j = 0; j < 8; ++j){
      float v = (m < 8) ? w3[(kb*32 + q*8 + j)*8 + m] : 0.0f;
      __bf16 hi = (__bf16)v;
      w3h[kb][j] = hi;
      w3l[kb][j] = (__bf16)(v - (float)hi);
    }
  }

  // ---- staging phase: zero w1f, fill w1f + w2f(half 0) + biases ----
  ((float4*)sm)[tid] = make_float4(0.0f, 0.0f, 0.0f, 0.0f);   // 512*16B = w1f
  __syncthreads();
  for (int idx = tid; idx < 15*256; idx += 512){   // w1: (k,n) k<15
    int k = idx >> 8, n = idx & 255;
    int ct = n >> 4;
    int l  = ((k>>3)*16) + (n & 15);
    int j  = k & 7;
    w1f[(ct*32 + l)*8 + j] = (__bf16)w1[idx];
  }
  for (int idx = tid; idx < 8192; idx += 512){     // w2 half 0: k in [0,128)
    int kk = idx >> 6, n = idx & 63;
    int kb2 = kk >> 5;
    int lq  = (kk >> 3) & 3;
    int j   = kk & 7;
    int ct  = n >> 4;
    int l   = lq*16 + (n & 15);
    w2f[((kb2*4 + ct)*64 + l)*8 + j] = (__bf16)w2[kk*64 + n];
  }
  if (tid < 256) b1s[tid] = b1[tid];
  if (tid < 64)  b2s[tid] = b2[tid];
  if (tid < 8)   b3s[tid] = b3[tid];
  __syncthreads();

  f32x4 zero4 = {0.0f, 0.0f, 0.0f, 0.0f};
  bf16x8 zero8;
  #pragma unroll
  for (int j = 0; j < 8; ++j) zero8[j] = (__bf16)0.0f;

  __bf16* hb = hbufA + wv*2304;                    // 32 rows x 72 bf16
  f32x4 acc2[2][4] = {{zero4, zero4, zero4, zero4},
                      {zero4, zero4, zero4, zero4}};

  #pragma unroll
  for (int pc = 0; pc < 2; ++pc){
    if (pc == 1){
      // restage w2f with half 1 (k in [128,256)); all waves' half-0 reads done
      __syncthreads();
      for (int idx = tid; idx < 8192; idx += 512){
        int kk = idx >> 6, n = idx & 63;
        int kb2 = kk >> 5;
        int lq  = (kk >> 3) & 3;
        int j   = kk & 7;
        int ct  = n >> 4;
        int l   = lq*16 + (n & 15);
        w2f[((kb2*4 + ct)*64 + l)*8 + j] = (__bf16)w2[(128 + kk)*64 + n];
      }
      __syncthreads();
    }
    #pragma unroll
    for (int ph = 0; ph < 2; ++ph){
      int p = pc*2 + ph;
      // ---- layer 1: h1 chunk (64 f) for both tiles, B-fragment shared ----
      #pragma unroll
      for (int c4 = 0; c4 < 4; ++c4){
        int ct = p*4 + c4;
        bf16x8 bw = zero8;
        if (lane < 32) bw = *(const bf16x8*)&w1f[(ct*32 + lane)*8];
        int f = c4*16 + m;
        float bb = b1s[p*64 + f];
        #pragma unroll
        for (int u = 0; u < 2; ++u){
          f32x4 c1 = __builtin_amdgcn_mfma_f32_16x16x32_bf16(a1[u], bw, zero4, 0, 0, 0);
          #pragma unroll
          for (int i = 0; i < 4; ++i){
            float h = tanh_f(c1[i] + bb);
            hb[(u*16 + q*4 + i)*72 + f] = (__bf16)h;
          }
        }
      }
      // ---- layer 2 partial: bw2 read once, used by both row tiles ----
      #pragma unroll
      for (int kb = 0; kb < 2; ++kb){
        bf16x8 a2_0 = *(const bf16x8*)&hb[ m      *72 + kb*32 + q*8];
        bf16x8 a2_1 = *(const bf16x8*)&hb[(16 + m)*72 + kb*32 + q*8];
        #pragma unroll
        for (int ct = 0; ct < 4; ++ct){
          bf16x8 bw2 = *(const bf16x8*)&w2f[(((ph*2 + kb)*4 + ct)*64 + lane)*8];
          acc2[0][ct] = __builtin_amdgcn_mfma_f32_16x16x32_bf16(a2_0, bw2, acc2[0][ct], 0, 0, 0);
          acc2[1][ct] = __builtin_amdgcn_mfma_f32_16x16x32_bf16(a2_1, bw2, acc2[1][ct], 0, 0, 0);
        }
      }
    }
  }

  // ---- layer 2 epilogue: h2 -> hb ----
  #pragma unroll
  for (int ct = 0; ct < 4; ++ct){
    int f = ct*16 + m;
    float bb = b2s[f];
    #pragma unroll
    for (int u = 0; u < 2; ++u)
      #pragma unroll
      for (int i = 0; i < 4; ++i){
        float h = tanh_f(acc2[u][ct][i] + bb);
        hb[(u*16 + q*4 + i)*72 + f] = (__bf16)h;
      }
  }

  // ---- layer 3 via MFMA: z3 = h2 @ (w3h + w3l) ----
  f32x4 acc3[2] = {zero4, zero4};
  #pragma unroll
  for (int kb = 0; kb < 2; ++kb){
    bf16x8 a3_0 = *(const bf16x8*)&hb[ m      *72 + kb*32 + q*8];
    bf16x8 a3_1 = *(const bf16x8*)&hb[(16 + m)*72 + kb*32 + q*8];
    acc3[0] = __builtin_amdgcn_mfma_f32_16x16x32_bf16(a3_0, w3h[kb], acc3[0], 0, 0, 0);
    acc3[0] = __builtin_amdgcn_mfma_f32_16x16x32_bf16(a3_0, w3l[kb], acc3[0], 0, 0, 0);
    acc3[1] = __builtin_amdgcn_mfma_f32_16x16x32_bf16(a3_1, w3h[kb], acc3[1], 0, 0, 0);
    acc3[1] = __builtin_amdgcn_mfma_f32_16x16x32_bf16(a3_1, w3l[kb], acc3[1], 0, 0, 0);
  }

  // ---- sigmoid + param exchange (stride-9 f32 scratch over hb) + pk4 reduce ----
  float* hf = (float*)hb;
  if (m < 8){
    float bb3 = b3s[m];
    #pragma unroll
    for (int u = 0; u < 2; ++u)
      #pragma unroll
      for (int i = 0; i < 4; ++i)
        hf[(u*16 + q*4 + i)*9 + m] = sigmoid_f(acc3[u][i] + bb3);
  }
  // same-wave DS ordering; compiler inserts lgkmcnt wait before dependent reads
  if (lane < 32){
    const float* Pr = hf + lane*9;
    float P0=Pr[0], P1=Pr[1], P2=Pr[2], P3=Pr[3];
    float P4=Pr[4], P5=Pr[5], P6=Pr[6], P7=Pr[7];
    // reference arg swap: _runoff(wu, wd, wl, p, wum, wdm, wlm, b, c)
    float wum = fmaf(P0, 19.9f, 0.1f);
    float wlm = fmaf(P2, 30.0f, 60.0f);     // wdm param lands in wlm slot
    float wdm = fmaf(P1, 60.0f, 60.0f);     // wlm param lands in wdm slot
    float wt  = wum + wlm + wdm;
    float rw  = 1.0f / wt;
    float cc  = fmaf(P4, 0.19f, 0.01f);
    float bc  = fmaf(P3, 0.30f, 0.10f);
    float A   = cc*rw*rw;
    float Bc  = bc*rw*rw;
    float k1  = fmaf(P5, 0.69f, 0.01f);
    float k2  = fmaf(P6, 0.69f, 0.01f);
    float k3  = fmaf(P7, 0.89f, 0.01f);
    float KP  = k1 + 0.5f*k2*(1.0f-k1) + 0.25f*k3*(1.0f-k1)*(1.0f-k2);
    *(float4*)&pk4[(size_t)(r0 + lane)*4] = make_float4(A, Bc, KP, 0.0f);
  }
}

// final pass: 512 blocks, 16t x 64b tiles (R8/R9/R10-verified tiling). Coalesced
// reads of t-major pT/wuT/wdT/pk4, LDS transpose, coalesced 64B out-row segments.
__global__ __launch_bounds__(256) void final_kernel(const float* __restrict__ ws,
                                                    float* __restrict__ out){
  __shared__ float tile[64*17];
  int tb = blockIdx.x >> 2;         // 0..127
  int bb = blockIdx.x & 3;          // 0..3
  int t0 = tb*16, b0 = bb*64;
  int tid = threadIdx.x;
  const float* pT   = ws;
  const float* wuT  = ws + 2*(size_t)NT;
  const float* wdT  = ws + 3*(size_t)NT;
  const float* pk4  = ws + 4*(size_t)NT;

  #pragma unroll
  for (int k = 0; k < 4; ++k){
    int idx = k*256 + tid;
    int tl = idx >> 6, bl = idx & 63;
    int r = (t0 + tl)*B_ + b0 + bl;
    float p  = pT[r];
    float wu = wuT[r], wd = wdT[r];
    float4 k4 = *(const float4*)&pk4[(size_t)r*4];
    float ps = p - k4.x*wu*wu - k4.y*wd*wd;
    float runoff = hside(ps)*ps;
    tile[bl*17 + tl] = k4.z * runoff;
  }
  __syncthreads();
  #pragma unroll
  for (int k = 0; k < 4; ++k){
    int idx = k*256 + tid;
    int tl2 = idx & 15, bl2 = idx >> 4;
    out[(size_t)(b0 + bl2)*T_ + t0 + tl2] = tile[bl2*17 + tl2];
  }
}

extern "C" void kernel_launch(void* const* d_in, const int* in_sizes, int n_in,
                              void* d_out, int out_size, void* d_ws, size_t ws_size,
                              hipStream_t stream) {
  const float* in = (const float*)d_in[0];
  const float* w1 = (const float*)d_in[1];
  const float* b1 = (const float*)d_in[2];
  const float* w2 = (const float*)d_in[3];
  const float* b2 = (const float*)d_in[4];
  const float* w3 = (const float*)d_in[5];
  const float* b3 = (const float*)d_in[6];
  float* out = (float*)d_out;
  float* ws  = (float*)d_ws;

  // scan path needs 73984 B dynamic LDS (ppL ring, 65-padded); raise cap once
  static bool attr_set = false;
  if (!attr_set){
    hipFuncSetAttribute((const void*)fused_kernel,
                        hipFuncAttributeMaxDynamicSharedMemorySize, 73984);
    attr_set = true;
  }

  fused_kernel<<<NT/256 + 4, 512, 73984, stream>>>(in, w1, b1, w2, b2, w3, b3, ws);
  final_kernel<<<512,        256, 0,     stream>>>(ws, out);
}

// Round 13
// 210.546 us; speedup vs baseline: 1.3472x; 1.3472x over previous
//
#include <hip/hip_runtime.h>

#define B_ 256
#define T_ 2048
#define F_ 20
#define NT (B_*T_)
#define CH 16
#define NCH (T_/CH)   // 128 chunks

typedef __bf16 bf16x8 __attribute__((ext_vector_type(8)));
typedef float  f32x4  __attribute__((ext_vector_type(4)));

__device__ __forceinline__ float ex2(float x){ return __builtin_amdgcn_exp2f(x); }
__device__ __forceinline__ float rcpf_(float x){ return __builtin_amdgcn_rcpf(x); }

// 20*log2(e), 2*log2(e), log2(e)
#define K10F 28.853900817779268f
#define K1F   2.8853900817779268f
#define LOG2E 1.4426950408889634f

__device__ __forceinline__ float hside(float x){ return 1.0f - rcpf_(ex2(K10F*x) + 1.0f); }
__device__ __forceinline__ float tanh_f(float z){ return 1.0f - 2.0f*rcpf_(ex2(K1F*z) + 1.0f); }
__device__ __forceinline__ float sigmoid_f(float z){ return rcpf_(1.0f + ex2(-LOG2E*z)); }

// LDS-only barrier: orders ds ops between stage waves WITHOUT draining vmcnt.
__device__ __forceinline__ void lds_barrier(){
  asm volatile("s_waitcnt lgkmcnt(0)" ::: "memory");
  __builtin_amdgcn_s_barrier();
  asm volatile("" ::: "memory");
}

// ws float layout (t-major r = t*256 + b):
// pp2 [0,2NT) float2{pet,p} | wuT [2NT,3NT) | wdT [3NT,4NT) | pk4 [4NT,8NT) float4{A,B,KP,_}

// Coalesced prep: 512 blocks each own a 64b x 16t tile.
// Read side: the tile's input rows are 80 contiguous float4 per row-chunk -> fully
// coalesced streams. Extract {pet,p} (j%5==0 float4 holds f0..f3), LDS transpose,
// then fully-coalesced float2 writes to t-major pp2.
// NOTE (R3/R8/R10/R12): in-layout reads must NOT live inside the 4-block scan —
// only a wide grid covers the strided-load latency. This prep stays a separate kernel.
__global__ __launch_bounds__(256) void prep_kernel(const float* __restrict__ in,
                                                   float* __restrict__ ws){
  __shared__ float2 t2[16][65];
  int t0 = (blockIdx.x >> 2) * 16;
  int b0 = (blockIdx.x & 3) * 64;
  int tid = threadIdx.x;
  const float4* in4 = (const float4*)in;
  #pragma unroll
  for (int k = 0; k < 20; ++k){
    int idx = k*256 + tid;           // 0..5119
    int bl = idx / 80;               // 0..63 (row within tile)
    int j  = idx % 80;               // float4 within row-chunk (16t*20f = 80 float4)
    float4 v = in4[(size_t)((b0 + bl)*T_ + t0)*5 + j];
    if (j % 5 == 0)                  // f0..f3 of timestep t_local=j/5: .x=pet, .z=p
      t2[j/5][bl] = make_float2(v.x, v.z);
  }
  __syncthreads();
  float2* pp2 = (float2*)ws;
  #pragma unroll
  for (int k = 0; k < 4; ++k){
    int idx = k*256 + tid;
    int tl = idx >> 6, bl2 = idx & 63;
    pp2[(t0 + tl)*B_ + b0 + bl2] = t2[tl][bl2];
  }
}

// blocks 0..3: pipelined scan (R0-verbatim body; LDS-only barrier)
// blocks 4..2051: MFMA MLP, 256 rows/block (R1-verbatim, verified)
__global__ __launch_bounds__(512) void fused_kernel(const float* __restrict__ in,
    const float* __restrict__ w1, const float* __restrict__ b1,
    const float* __restrict__ w2, const float* __restrict__ b2,
    const float* __restrict__ w3, const float* __restrict__ b3,
    float* __restrict__ ws){
  extern __shared__ char sm[];
  float* pk4 = ws + 4*(size_t)NT;

  if (blockIdx.x < 4) {
    // ================== pipelined Xinanjiang scan ==================
    asm volatile("s_setprio 3");            // scan waves win issue arbitration vs MLP waves
    const float2* pp2 = (const float2*)ws;
    float* wuT = ws + 2*(size_t)NT;
    float* wdT = ws + 3*(size_t)NT;
    float*  d1L = (float*)sm;                  // [2][CH][64]   8 KB
    float*  bsQ = (float*)(sm + 8192);         // [4][CH][64]  16 KB
    float2* rhL = (float2*)(sm + 24576);       // [2][CH][64]  16 KB {rp,hrp}
    float2* qbL = (float2*)(sm + 40960);       // [2][CH][64]  16 KB {qv,b2}

    int tid = threadIdx.x;
    int wv = tid >> 6, lane = tid & 63;
    int boff = blockIdx.x * 64;

    float wu = 0.0f, wl = 0.0f, wd = 0.0f;
    float2 buf[2][8];

    if (wv == 0){
      #pragma unroll
      for (int g = 0; g < 2; ++g)
        #pragma unroll
        for (int i = 0; i < 8; ++i)
          buf[g][i] = pp2[(g*8 + i)*B_ + boff + lane];
    }

    for (int it = 0; it < NCH + 3; ++it){
      if (wv == 0){
        if (it < NCH){
          int c = it, par = c & 1;
          #pragma unroll
          for (int g = 0; g < 2; ++g){
            #pragma unroll
            for (int i = 0; i < 8; ++i){
              int s = g*8 + i;
              float pet = buf[g][i].x, p = buf[g][i].y;
              float d  = wu - pet;
              float r1 = rcpf_(ex2(K10F*d) + 1.0f);
              float d1 = -d*r1;                       // pet - et1
              float base = (p - pet) + d1;            // p - et1
              wu += base;
              wuT[(c*CH + s)*B_ + boff + lane] = wu;
              d1L[par*(CH*64) + s*64 + lane] = d1;
              bsQ[(c&3)*(CH*64) + s*64 + lane] = base;
            }
            int cn = (c + 1 < NCH) ? c + 1 : c;       // prefetch next chunk, same group
            #pragma unroll
            for (int i = 0; i < 8; ++i)
              buf[g][i] = pp2[(cn*CH + g*8 + i)*B_ + boff + lane];
          }
        }
      } else if (wv == 1){
        if (it >= 1 && it <= NCH){
          int c = it - 1, par = c & 1;
          #pragma unroll
          for (int s = 0; s < CH; ++s){
            float d1 = d1L[par*(CH*64) + s*64 + lane];
            float r2 = rcpf_(ex2(K10F*d1) + 1.0f);
            float rp = fmaf(-d1, r2, d1);             // h(d1)*d1
            float hrp = 1.0f - rcpf_(ex2(K10F*rp) + 1.0f);
            rhL[par*(CH*64) + s*64 + lane] = make_float2(rp, hrp);
          }
        }
      } else if (wv == 2){
        if (it >= 2 && it <= NCH + 1){
          int c = it - 2, par = c & 1;
          #pragma unroll
          for (int s = 0; s < CH; ++s){
            float2 rh  = rhL[par*(CH*64) + s*64 + lane];
            float base = bsQ[(c&3)*(CH*64) + s*64 + lane];
            float d2   = rh.x - wl;
            float r    = rcpf_(ex2(K10F*d2) + 1.0f);
            float et22 = fmaf(d2, r, wl);
            float et2  = rh.y * et22;
            float b2v  = base - et2;
            wl += b2v;
            qbL[par*(CH*64) + s*64 + lane] = make_float2(rh.x - et2, b2v); // qv, b2
          }
        }
      } else if (wv == 3){
        if (it >= 3){
          int c = it - 3, par = c & 1;
          #pragma unroll
          for (int s = 0; s < CH; ++s){
            float2 qb  = qbL[par*(CH*64) + s*64 + lane];
            float hqv  = 1.0f - rcpf_(ex2(K10F*qb.x) + 1.0f);
            float d3   = qb.x - wd;
            float r    = rcpf_(ex2(K10F*d3) + 1.0f);
            float et33 = fmaf(d3, r, wd);
            float et3  = hqv * et33;
            wd += qb.y - et3;
            wdT[(c*CH + s)*B_ + boff + lane] = wd;
          }
        }
      }
      lds_barrier();   // LDS-only ordering; wuT/wdT stores stay in flight
    }
    return;
  }

  // ================== MFMA MLP path: 32 rows per wave (R1-verbatim) ==================
  // LDS map:
  // w1f [0,8192) | w2f half [8192,24576) | b1s [24576,25600) | b2s [25600,25856)
  // b3s [25856,25888) | hbufA [25888,62752): 8 waves x 32 rows x 72 bf16
  __bf16* w1f   = (__bf16*)sm;
  __bf16* w2f   = (__bf16*)(sm + 8192);
  float*  b1s   = (float*)(sm + 24576);
  float*  b2s   = (float*)(sm + 25600);
  float*  b3s   = (float*)(sm + 25856);
  __bf16* hbufA = (__bf16*)(sm + 25888);

  int tid  = threadIdx.x;
  int lane = tid & 63;
  int wv   = tid >> 6;
  int m    = lane & 15;
  int q    = lane >> 4;
  int r0   = (blockIdx.x - 4)*256 + wv*32;   // t-major r, 32 rows per wave

  // ---- early global loads (latency hidden under staging) ----
  bf16x8 a1[2];
  #pragma unroll
  for (int u = 0; u < 2; ++u){
    int rowA = r0 + u*16 + m;
    int bA = rowA & (B_-1), tA = rowA >> 8;
    const float* ap = in + ((size_t)bA*T_ + tA)*F_ + 5;
    #pragma unroll
    for (int j = 0; j < 8; ++j){
      int k = q*8 + j;
      a1[u][j] = (__bf16)((k < 15) ? ap[k] : 0.0f);
    }
  }
  // w3 B-fragments in registers, split hi+lo bf16 so z3 is f32-accurate.
  bf16x8 w3h[2], w3l[2];
  #pragma unroll
  for (int kb = 0; kb < 2; ++kb){
    #pragma unroll
    for (int j = 0; j < 8; ++j){
      float v = (m < 8) ? w3[(kb*32 + q*8 + j)*8 + m] : 0.0f;
      __bf16 hi = (__bf16)v;
      w3h[kb][j] = hi;
      w3l[kb][j] = (__bf16)(v - (float)hi);
    }
  }

  // ---- staging phase: zero w1f, fill w1f + w2f(half 0) + biases ----
  ((float4*)sm)[tid] = make_float4(0.0f, 0.0f, 0.0f, 0.0f);   // 512*16B = w1f
  __syncthreads();
  for (int idx = tid; idx < 15*256; idx += 512){   // w1: (k,n) k<15
    int k = idx >> 8, n = idx & 255;
    int ct = n >> 4;
    int l  = ((k>>3)*16) + (n & 15);
    int j  = k & 7;
    w1f[(ct*32 + l)*8 + j] = (__bf16)w1[idx];
  }
  for (int idx = tid; idx < 8192; idx += 512){     // w2 half 0: k in [0,128)
    int kk = idx >> 6, n = idx & 63;
    int kb2 = kk >> 5;
    int lq  = (kk >> 3) & 3;
    int j   = kk & 7;
    int ct  = n >> 4;
    int l   = lq*16 + (n & 15);
    w2f[((kb2*4 + ct)*64 + l)*8 + j] = (__bf16)w2[kk*64 + n];
  }
  if (tid < 256) b1s[tid] = b1[tid];
  if (tid < 64)  b2s[tid] = b2[tid];
  if (tid < 8)   b3s[tid] = b3[tid];
  __syncthreads();

  f32x4 zero4 = {0.0f, 0.0f, 0.0f, 0.0f};
  bf16x8 zero8;
  #pragma unroll
  for (int j = 0; j < 8; ++j) zero8[j] = (__bf16)0.0f;

  __bf16* hb = hbufA + wv*2304;                    // 32 rows x 72 bf16
  f32x4 acc2[2][4] = {{zero4, zero4, zero4, zero4},
                      {zero4, zero4, zero4, zero4}};

  #pragma unroll
  for (int pc = 0; pc < 2; ++pc){
    if (pc == 1){
      // restage w2f with half 1 (k in [128,256)); all waves' half-0 reads done
      __syncthreads();
      for (int idx = tid; idx < 8192; idx += 512){
        int kk = idx >> 6, n = idx & 63;
        int kb2 = kk >> 5;
        int lq  = (kk >> 3) & 3;
        int j   = kk & 7;
        int ct  = n >> 4;
        int l   = lq*16 + (n & 15);
        w2f[((kb2*4 + ct)*64 + l)*8 + j] = (__bf16)w2[(128 + kk)*64 + n];
      }
      __syncthreads();
    }
    #pragma unroll
    for (int ph = 0; ph < 2; ++ph){
      int p = pc*2 + ph;
      // ---- layer 1: h1 chunk (64 f) for both tiles, B-fragment shared ----
      #pragma unroll
      for (int c4 = 0; c4 < 4; ++c4){
        int ct = p*4 + c4;
        bf16x8 bw = zero8;
        if (lane < 32) bw = *(const bf16x8*)&w1f[(ct*32 + lane)*8];
        int f = c4*16 + m;
        float bb = b1s[p*64 + f];
        #pragma unroll
        for (int u = 0; u < 2; ++u){
          f32x4 c1 = __builtin_amdgcn_mfma_f32_16x16x32_bf16(a1[u], bw, zero4, 0, 0, 0);
          #pragma unroll
          for (int i = 0; i < 4; ++i){
            float h = tanh_f(c1[i] + bb);
            hb[(u*16 + q*4 + i)*72 + f] = (__bf16)h;
          }
        }
      }
      // ---- layer 2 partial: bw2 read once, used by both row tiles ----
      #pragma unroll
      for (int kb = 0; kb < 2; ++kb){
        bf16x8 a2_0 = *(const bf16x8*)&hb[ m      *72 + kb*32 + q*8];
        bf16x8 a2_1 = *(const bf16x8*)&hb[(16 + m)*72 + kb*32 + q*8];
        #pragma unroll
        for (int ct = 0; ct < 4; ++ct){
          bf16x8 bw2 = *(const bf16x8*)&w2f[(((ph*2 + kb)*4 + ct)*64 + lane)*8];
          acc2[0][ct] = __builtin_amdgcn_mfma_f32_16x16x32_bf16(a2_0, bw2, acc2[0][ct], 0, 0, 0);
          acc2[1][ct] = __builtin_amdgcn_mfma_f32_16x16x32_bf16(a2_1, bw2, acc2[1][ct], 0, 0, 0);
        }
      }
    }
  }

  // ---- layer 2 epilogue: h2 -> hb ----
  #pragma unroll
  for (int ct = 0; ct < 4; ++ct){
    int f = ct*16 + m;
    float bb = b2s[f];
    #pragma unroll
    for (int u = 0; u < 2; ++u)
      #pragma unroll
      for (int i = 0; i < 4; ++i){
        float h = tanh_f(acc2[u][ct][i] + bb);
        hb[(u*16 + q*4 + i)*72 + f] = (__bf16)h;
      }
  }

  // ---- layer 3 via MFMA: z3 = h2 @ (w3h + w3l) ----
  f32x4 acc3[2] = {zero4, zero4};
  #pragma unroll
  for (int kb = 0; kb < 2; ++kb){
    bf16x8 a3_0 = *(const bf16x8*)&hb[ m      *72 + kb*32 + q*8];
    bf16x8 a3_1 = *(const bf16x8*)&hb[(16 + m)*72 + kb*32 + q*8];
    acc3[0] = __builtin_amdgcn_mfma_f32_16x16x32_bf16(a3_0, w3h[kb], acc3[0], 0, 0, 0);
    acc3[0] = __builtin_amdgcn_mfma_f32_16x16x32_bf16(a3_0, w3l[kb], acc3[0], 0, 0, 0);
    acc3[1] = __builtin_amdgcn_mfma_f32_16x16x32_bf16(a3_1, w3h[kb], acc3[1], 0, 0, 0);
    acc3[1] = __builtin_amdgcn_mfma_f32_16x16x32_bf16(a3_1, w3l[kb], acc3[1], 0, 0, 0);
  }

  // ---- sigmoid + param exchange (stride-9 f32 scratch over hb) + pk4 reduce ----
  float* hf = (float*)hb;
  if (m < 8){
    float bb3 = b3s[m];
    #pragma unroll
    for (int u = 0; u < 2; ++u)
      #pragma unroll
      for (int i = 0; i < 4; ++i)
        hf[(u*16 + q*4 + i)*9 + m] = sigmoid_f(acc3[u][i] + bb3);
  }
  // same-wave DS ordering; compiler inserts lgkmcnt wait before dependent reads
  if (lane < 32){
    const float* Pr = hf + lane*9;
    float P0=Pr[0], P1=Pr[1], P2=Pr[2], P3=Pr[3];
    float P4=Pr[4], P5=Pr[5], P6=Pr[6], P7=Pr[7];
    // reference arg swap: _runoff(wu, wd, wl, p, wum, wdm, wlm, b, c)
    float wum = fmaf(P0, 19.9f, 0.1f);
    float wlm = fmaf(P2, 30.0f, 60.0f);     // wdm param lands in wlm slot
    float wdm = fmaf(P1, 60.0f, 60.0f);     // wlm param lands in wdm slot
    float wt  = wum + wlm + wdm;
    float rw  = 1.0f / wt;
    float cc  = fmaf(P4, 0.19f, 0.01f);
    float bc  = fmaf(P3, 0.30f, 0.10f);
    float A   = cc*rw*rw;
    float Bc  = bc*rw*rw;
    float k1  = fmaf(P5, 0.69f, 0.01f);
    float k2  = fmaf(P6, 0.69f, 0.01f);
    float k3  = fmaf(P7, 0.89f, 0.01f);
    float KP  = k1 + 0.5f*k2*(1.0f-k1) + 0.25f*k3*(1.0f-k1)*(1.0f-k2);
    *(float4*)&pk4[(size_t)(r0 + lane)*4] = make_float4(A, Bc, KP, 0.0f);
  }
}

// final pass: 512 blocks, 16t x 64b tiles (R8/R9/R11-verified tiling). Coalesced
// reads of t-major arrays, LDS transpose, coalesced 64B out-row segments.
__global__ __launch_bounds__(256) void final_kernel(const float* __restrict__ ws,
                                                    float* __restrict__ out){
  __shared__ float tile[64*17];
  int tb = blockIdx.x >> 2;         // 0..127
  int bb = blockIdx.x & 3;          // 0..3
  int t0 = tb*16, b0 = bb*64;
  int tid = threadIdx.x;
  const float2* pp2 = (const float2*)ws;
  const float* wuT  = ws + 2*(size_t)NT;
  const float* wdT  = ws + 3*(size_t)NT;
  const float* pk4  = ws + 4*(size_t)NT;

  #pragma unroll
  for (int k = 0; k < 4; ++k){
    int idx = k*256 + tid;
    int tl = idx >> 6, bl = idx & 63;
    int r = (t0 + tl)*B_ + b0 + bl;
    float p  = pp2[r].y;
    float wu = wuT[r], wd = wdT[r];
    float4 k4 = *(const float4*)&pk4[(size_t)r*4];
    float ps = p - k4.x*wu*wu - k4.y*wd*wd;
    float runoff = hside(ps)*ps;
    tile[bl*17 + tl] = k4.z * runoff;
  }
  __syncthreads();
  #pragma unroll
  for (int k = 0; k < 4; ++k){
    int idx = k*256 + tid;
    int tl2 = idx & 15, bl2 = idx >> 4;
    out[(size_t)(b0 + bl2)*T_ + t0 + tl2] = tile[bl2*17 + tl2];
  }
}

extern "C" void kernel_launch(void* const* d_in, const int* in_sizes, int n_in,
                              void* d_out, int out_size, void* d_ws, size_t ws_size,
                              hipStream_t stream) {
  const float* in = (const float*)d_in[0];
  const float* w1 = (const float*)d_in[1];
  const float* b1 = (const float*)d_in[2];
  const float* w2 = (const float*)d_in[3];
  const float* b2 = (const float*)d_in[4];
  const float* w3 = (const float*)d_in[5];
  const float* b3 = (const float*)d_in[6];
  float* out = (float*)d_out;
  float* ws  = (float*)d_ws;

  prep_kernel <<<512,        256, 0,     stream>>>(in, ws);
  fused_kernel<<<NT/256 + 4, 512, 62752, stream>>>(in, w1, b1, w2, b2, w3, b3, ws);
  final_kernel<<<512,        256, 0,     stream>>>(ws, out);
}